// Round 3
// baseline (175.289 us; speedup 1.0000x reference)
//
#include <hip/hip_runtime.h>

// RFCN PSROI — algebraic restructure:
//   out[b,n,g] = B'[g] + (1/denom) * sum_{bin} Z[b,g,h,w]
//   Z = einsum('bchw,gc->bghw', features, W'),  W'[g,c] = sum_k w[g*9+k, c]
// Pipeline: (1) fold weights, (2) project features -> 25-ch score map Z
// (chunked over channels into partials for determinism), (3) reduce partials +
// 2D inclusive prefix-sum (integral image) per (b,g), (4) per-proposal
// 4-corner gather.

#define HW 4096      // 64*64
#define NG 25        // 21 cls + 4 reg groups
#define CIN 1024
#define B 2
#define NPROP 1000

// ---------------- Kernel 1: fold weights over the K*K=9 channel groups ----
__global__ void rfcn_wfold(const float* __restrict__ w_cls,
                           const float* __restrict__ b_cls,
                           const float* __restrict__ w_reg,
                           const float* __restrict__ b_reg,
                           float* __restrict__ Wred,   // [25][1024]
                           float* __restrict__ Bred) { // [25]
    int i = blockIdx.x * 256 + threadIdx.x;
    if (i < NG * CIN) {
        int g = i >> 10, c = i & (CIN - 1);
        float s = 0.f;
        if (g < 21) {
            #pragma unroll
            for (int k = 0; k < 9; ++k) s += w_cls[(size_t)(g * 9 + k) * CIN + c];
        } else {
            int gr = g - 21;
            #pragma unroll
            for (int k = 0; k < 9; ++k) s += w_reg[(size_t)(gr * 9 + k) * CIN + c];
        }
        Wred[i] = s;
    } else if (i < NG * CIN + NG) {
        int g = i - NG * CIN;
        float s = 0.f;
        if (g < 21) {
            #pragma unroll
            for (int k = 0; k < 9; ++k) s += b_cls[g * 9 + k];
        } else {
            #pragma unroll
            for (int k = 0; k < 9; ++k) s += b_reg[(g - 21) * 9 + k];
        }
        Bred[g] = s;
    }
}

// ---------------- Kernel 2: projection  Z_partial = W' x F (channel chunk) --
// grid = (16 pixel tiles, NCH chunks, B), block = 256 (1 pixel/thread).
// part layout: [chunk][b][g][4096]
__global__ __launch_bounds__(256)
void rfcn_proj(const float* __restrict__ feats,
               const float* __restrict__ Wred,
               float* __restrict__ part, int CK) {
    const int p = blockIdx.x * 256 + threadIdx.x;   // pixel in [0,4096)
    const int chunk = blockIdx.y;
    const int b = blockIdx.z;
    const int c0 = chunk * CK;

    const float* __restrict__ f = feats + ((size_t)b * CIN + c0) * HW + p;
    const float* __restrict__ w = Wred + c0;   // uniform accesses -> s_load

    float acc[NG];
    #pragma unroll
    for (int g = 0; g < NG; ++g) acc[g] = 0.f;

    #pragma unroll 4
    for (int c = 0; c < CK; ++c) {
        float fv = f[(size_t)c * HW];
        #pragma unroll
        for (int g = 0; g < NG; ++g) acc[g] += fv * w[g * CIN + c];
    }

    float* __restrict__ o = part + ((size_t)(chunk * B + b) * NG) * HW + p;
    #pragma unroll
    for (int g = 0; g < NG; ++g) o[(size_t)g * HW] = acc[g];
}

// ---------------- Kernel 3: reduce partials + 2D inclusive prefix sum ------
// grid = 50 (m = b*25+g), block = 64 (one wave). LDS 64x65 (pad kills
// the 64-stride bank conflict in the row-scan phase).
__global__ __launch_bounds__(64)
void rfcn_integral(const float* __restrict__ part,
                   float* __restrict__ IZ, int NCH) {
    const int m = blockIdx.x;        // b*25 + g
    const int t = threadIdx.x;       // 0..63
    __shared__ float tile[64 * 65];

    for (int r = 0; r < 64; ++r) {
        int fidx = r * 64 + t;
        float s = 0.f;
        for (int ch = 0; ch < NCH; ++ch)
            s += part[(size_t)(ch * (B * NG) + m) * HW + fidx];
        tile[r * 65 + t] = s;
    }
    __syncthreads();
    // row prefix: thread t scans row t (padded stride -> conflict-free)
    float run = 0.f;
    for (int j = 0; j < 64; ++j) { run += tile[t * 65 + j]; tile[t * 65 + j] = run; }
    __syncthreads();
    // column prefix: thread t scans column t (consecutive addrs across lanes)
    run = 0.f;
    for (int r = 0; r < 64; ++r) { run += tile[r * 65 + t]; tile[r * 65 + t] = run; }
    __syncthreads();
    for (int r = 0; r < 64; ++r)
        IZ[(size_t)m * HW + r * 64 + t] = tile[r * 65 + t];
}

// ---------------- Kernel 4: per-proposal 4-corner gather -------------------
// grid = 2000 (pid = b*1000+n), block = 64 (lanes 0..24 active).
__global__ __launch_bounds__(64)
void rfcn_gather(const int* __restrict__ props,
                 const float* __restrict__ IZ,
                 const float* __restrict__ Bred,
                 float* __restrict__ out) {
    const int pid = blockIdx.x;              // b*1000 + n
    const int g = threadIdx.x;
    const int b = pid / NPROP;

    const int4 pr = ((const int4*)props)[pid];
    const int x1 = pr.x >> 5;                // floor(px/32), px >= 0
    const int y1 = pr.y >> 5;
    const int x2 = (pr.z + 31) >> 5;         // ceil
    const int y2 = (pr.w + 31) >> 5;
    const int wb = (x2 - x1 + 2) / 3;        // ceil((x2-x1)/3), >=1
    const int hb = (y2 - y1 + 2) / 3;
    const int c2 = x1 + wb - 1;              // inclusive corner, <= 63
    const int r2 = y1 + hb - 1;

    if (g < NG) {
        const float* __restrict__ I = IZ + (size_t)(b * NG + g) * HW;
        float s = I[r2 * 64 + c2];
        if (x1 > 0)           s -= I[r2 * 64 + (x1 - 1)];
        if (y1 > 0)           s -= I[(y1 - 1) * 64 + c2];
        if (x1 > 0 && y1 > 0) s += I[(y1 - 1) * 64 + (x1 - 1)];
        float v = Bred[g] + s / (float)(hb * wb);
        if (g < 21) out[(size_t)pid * 21 + g] = v;                      // cls
        else        out[(size_t)(B * NPROP * 21) + (size_t)pid * 4 + (g - 21)] = v; // reg
    }
}

extern "C" void kernel_launch(void* const* d_in, const int* in_sizes, int n_in,
                              void* d_out, int out_size, void* d_ws, size_t ws_size,
                              hipStream_t stream) {
    const float* feats = (const float*)d_in[0];  // [2,1024,64,64]
    const float* w_cls = (const float*)d_in[1];  // [189,1024]
    const float* b_cls = (const float*)d_in[2];  // [189]
    const float* w_reg = (const float*)d_in[3];  // [36,1024]
    const float* b_reg = (const float*)d_in[4];  // [36]
    const int*   props = (const int*)d_in[5];    // [2,1000,4]
    float* out = (float*)d_out;
    float* ws  = (float*)d_ws;

    // workspace layout (floats)
    float* Wred = ws;                 // 25600
    float* Bred = ws + 25600;         // 25 (start partials at 25632, 128B-aligned)
    float* part = ws + 25632;         // NCH * 2 * 25 * 4096

    // pick the largest channel-chunk count that fits the workspace
    const size_t per_chunk = (size_t)B * NG * HW;          // 204800 floats
    int NCH = 8;
    while (NCH > 1 &&
           (size_t)(25632 + (size_t)NCH * per_chunk + per_chunk) * sizeof(float) > ws_size)
        NCH >>= 1;
    float* IZ = part + (size_t)NCH * per_chunk;            // 2*25*4096
    const int CK = CIN / NCH;

    rfcn_wfold<<<(NG * CIN + NG + 255) / 256, 256, 0, stream>>>(
        w_cls, b_cls, w_reg, b_reg, Wred, Bred);
    rfcn_proj<<<dim3(HW / 256, NCH, B), 256, 0, stream>>>(feats, Wred, part, CK);
    rfcn_integral<<<B * NG, 64, 0, stream>>>(part, IZ, NCH);
    rfcn_gather<<<B * NPROP, 64, 0, stream>>>(props, IZ, Bred, out);
}

// Round 4
// 63.418 us; speedup vs baseline: 2.7641x; 2.7641x over previous
//
#include <hip/hip_runtime.h>

// RFCN PSROI — algebraic restructure:
//   out[b,n,g] = B'[g] + (1/denom) * sum_{bin} Z[b,g,h,w]
//   Z = einsum('bchw,gc->bghw', features, W'),  W'[g,c] = sum_k w[g*9+k, c]
// Pipeline: (1) fold weights, (2) project features -> 25-ch score map Z
// (chunked over channels into partials for determinism), (3) reduce partials +
// 2D inclusive prefix-sum via wave-parallel shfl scans, (4) per-proposal
// 4-corner gather.

#define HW 4096      // 64*64
#define NG 25        // 21 cls + 4 reg groups
#define CIN 1024
#define B 2
#define NPROP 1000

// ---------------- Kernel 1: fold weights over the K*K=9 channel groups ----
__global__ void rfcn_wfold(const float* __restrict__ w_cls,
                           const float* __restrict__ b_cls,
                           const float* __restrict__ w_reg,
                           const float* __restrict__ b_reg,
                           float* __restrict__ Wred,   // [25][1024]
                           float* __restrict__ Bred) { // [25]
    int i = blockIdx.x * 256 + threadIdx.x;
    if (i < NG * CIN) {
        int g = i >> 10, c = i & (CIN - 1);
        float s = 0.f;
        if (g < 21) {
            #pragma unroll
            for (int k = 0; k < 9; ++k) s += w_cls[(size_t)(g * 9 + k) * CIN + c];
        } else {
            int gr = g - 21;
            #pragma unroll
            for (int k = 0; k < 9; ++k) s += w_reg[(size_t)(gr * 9 + k) * CIN + c];
        }
        Wred[i] = s;
    } else if (i < NG * CIN + NG) {
        int g = i - NG * CIN;
        float s = 0.f;
        if (g < 21) {
            #pragma unroll
            for (int k = 0; k < 9; ++k) s += b_cls[g * 9 + k];
        } else {
            #pragma unroll
            for (int k = 0; k < 9; ++k) s += b_reg[(g - 21) * 9 + k];
        }
        Bred[g] = s;
    }
}

// ---------------- Kernel 2: projection  Z_partial = W' x F (channel chunk) --
// grid = (16 pixel tiles, NCH chunks, B), block = 256 (1 pixel/thread).
// part layout: [chunk][b][g][4096]
__global__ __launch_bounds__(256)
void rfcn_proj(const float* __restrict__ feats,
               const float* __restrict__ Wred,
               float* __restrict__ part, int CK) {
    const int p = blockIdx.x * 256 + threadIdx.x;   // pixel in [0,4096)
    const int chunk = blockIdx.y;
    const int b = blockIdx.z;
    const int c0 = chunk * CK;

    const float* __restrict__ f = feats + ((size_t)b * CIN + c0) * HW + p;
    const float* __restrict__ w = Wred + c0;   // uniform indices -> s_load

    float acc[NG];
    #pragma unroll
    for (int g = 0; g < NG; ++g) acc[g] = 0.f;

    #pragma unroll 4
    for (int c = 0; c < CK; ++c) {
        float fv = f[(size_t)c * HW];
        #pragma unroll
        for (int g = 0; g < NG; ++g) acc[g] += fv * w[g * CIN + c];
    }

    float* __restrict__ o = part + ((size_t)(chunk * B + b) * NG) * HW + p;
    #pragma unroll
    for (int g = 0; g < NG; ++g) o[(size_t)g * HW] = acc[g];
}

// ---------------- Kernel 3: reduce partials + 2D prefix sum (wave scans) ---
// grid = 50 (m = b*25+g), block = 256 (4 waves).
// LDS 64x65: pad keeps row phase conflict-free; col phase stride 65 == 1
// (mod 32) -> distinct banks per lane (2-way lane/lane+32 alias is free).
__global__ __launch_bounds__(256)
void rfcn_integral(const float* __restrict__ part,
                   float* __restrict__ IZ, int NCH) {
    const int m = blockIdx.x;        // b*25 + g
    const int t = threadIdx.x;
    const int lane = t & 63;
    const int wave = t >> 6;
    __shared__ float tile[64 * 65];

    // phase 1: reduce NCH partial chunks, fully coalesced
    #pragma unroll
    for (int i = 0; i < 16; ++i) {
        const int idx = i * 256 + t;
        float s = 0.f;
        #pragma unroll 4
        for (int ch = 0; ch < NCH; ++ch)
            s += part[(size_t)(ch * (B * NG) + m) * HW + idx];
        tile[(idx >> 6) * 65 + (idx & 63)] = s;
    }
    __syncthreads();

    // phase 2: row scans — wave w owns rows [w*16, w*16+16), lane = column
    #pragma unroll 2
    for (int i = 0; i < 16; ++i) {
        const int row = wave * 16 + i;
        float v = tile[row * 65 + lane];
        #pragma unroll
        for (int d = 1; d < 64; d <<= 1) {
            float u = __shfl_up(v, (unsigned)d, 64);
            if (lane >= d) v += u;
        }
        tile[row * 65 + lane] = v;
    }
    __syncthreads();

    // phase 3: column scans — wave w owns cols [w*16, w*16+16), lane = row
    #pragma unroll 2
    for (int i = 0; i < 16; ++i) {
        const int col = wave * 16 + i;
        float v = tile[lane * 65 + col];
        #pragma unroll
        for (int d = 1; d < 64; d <<= 1) {
            float u = __shfl_up(v, (unsigned)d, 64);
            if (lane >= d) v += u;
        }
        tile[lane * 65 + col] = v;
    }
    __syncthreads();

    // phase 4: coalesced store
    #pragma unroll
    for (int i = 0; i < 16; ++i) {
        const int idx = i * 256 + t;
        IZ[(size_t)m * HW + idx] = tile[(idx >> 6) * 65 + (idx & 63)];
    }
}

// ---------------- Kernel 4: per-proposal 4-corner gather -------------------
// grid = 2000 (pid = b*1000+n), block = 64 (lanes 0..24 active).
__global__ __launch_bounds__(64)
void rfcn_gather(const int* __restrict__ props,
                 const float* __restrict__ IZ,
                 const float* __restrict__ Bred,
                 float* __restrict__ out) {
    const int pid = blockIdx.x;              // b*1000 + n
    const int g = threadIdx.x;
    const int b = pid / NPROP;

    const int4 pr = ((const int4*)props)[pid];
    const int x1 = pr.x >> 5;                // floor(px/32), px >= 0
    const int y1 = pr.y >> 5;
    const int x2 = (pr.z + 31) >> 5;         // ceil
    const int y2 = (pr.w + 31) >> 5;
    const int wb = (x2 - x1 + 2) / 3;        // ceil((x2-x1)/3), >=1
    const int hb = (y2 - y1 + 2) / 3;
    const int c2 = x1 + wb - 1;              // inclusive corner, <= 63
    const int r2 = y1 + hb - 1;

    if (g < NG) {
        const float* __restrict__ I = IZ + (size_t)(b * NG + g) * HW;
        float s = I[r2 * 64 + c2];
        if (x1 > 0)           s -= I[r2 * 64 + (x1 - 1)];
        if (y1 > 0)           s -= I[(y1 - 1) * 64 + c2];
        if (x1 > 0 && y1 > 0) s += I[(y1 - 1) * 64 + (x1 - 1)];
        float v = Bred[g] + s / (float)(hb * wb);
        if (g < 21) out[(size_t)pid * 21 + g] = v;                      // cls
        else        out[(size_t)(B * NPROP * 21) + (size_t)pid * 4 + (g - 21)] = v; // reg
    }
}

extern "C" void kernel_launch(void* const* d_in, const int* in_sizes, int n_in,
                              void* d_out, int out_size, void* d_ws, size_t ws_size,
                              hipStream_t stream) {
    const float* feats = (const float*)d_in[0];  // [2,1024,64,64]
    const float* w_cls = (const float*)d_in[1];  // [189,1024]
    const float* b_cls = (const float*)d_in[2];  // [189]
    const float* w_reg = (const float*)d_in[3];  // [36,1024]
    const float* b_reg = (const float*)d_in[4];  // [36]
    const int*   props = (const int*)d_in[5];    // [2,1000,4]
    float* out = (float*)d_out;
    float* ws  = (float*)d_ws;

    // workspace layout (floats)
    float* Wred = ws;                 // 25600
    float* Bred = ws + 25600;         // 25 (partials start at 25632, 128B-aligned)
    float* part = ws + 25632;         // NCH * 2 * 25 * 4096

    // largest channel-chunk count that fits the workspace (16 -> 8 -> ...)
    const size_t per_chunk = (size_t)B * NG * HW;          // 204800 floats
    int NCH = 16;
    while (NCH > 1 &&
           (size_t)(25632 + (size_t)NCH * per_chunk + per_chunk) * sizeof(float) > ws_size)
        NCH >>= 1;
    float* IZ = part + (size_t)NCH * per_chunk;            // 2*25*4096
    const int CK = CIN / NCH;

    rfcn_wfold<<<(NG * CIN + NG + 255) / 256, 256, 0, stream>>>(
        w_cls, b_cls, w_reg, b_reg, Wred, Bred);
    rfcn_proj<<<dim3(HW / 256, NCH, B), 256, 0, stream>>>(feats, Wred, part, CK);
    rfcn_integral<<<B * NG, 256, 0, stream>>>(part, IZ, NCH);
    rfcn_gather<<<B * NPROP, 64, 0, stream>>>(props, IZ, Bred, out);
}

// Round 5
// 43.664 us; speedup vs baseline: 4.0145x; 1.4524x over previous
//
#include <hip/hip_runtime.h>

// RFCN PSROI — algebraic restructure:
//   out[b,n,g] = B'[g] + (1/denom) * sum_{bin} Z[b,g,h,w]
//   Z = einsum('bchw,gc->bghw', features, W'),  W'[g,c] = sum_k w[g*9+k, c]
// Pipeline: (1) fold weights, (2) project features -> 25-ch score map Z
// (16 channel-chunks into partials for determinism), (3) one kernel per (b,g):
// reduce partials + 2D prefix sum in LDS + per-proposal 4-corner gather
// straight from LDS (no integral-image round trip, no 4th launch).

#define HW 4096      // 64*64
#define NG 25        // 21 cls + 4 reg groups
#define CIN 1024
#define B 2
#define NPROP 1000
#define NCH 16       // channel chunks (ws is 268 MB; needs ~13.3 MB)
#define CK (CIN / NCH)

// ---------------- Kernel 1: fold weights over the K*K=9 channel groups ----
__global__ void rfcn_wfold(const float* __restrict__ w_cls,
                           const float* __restrict__ b_cls,
                           const float* __restrict__ w_reg,
                           const float* __restrict__ b_reg,
                           float* __restrict__ Wred,   // [25][1024]
                           float* __restrict__ Bred) { // [25]
    int i = blockIdx.x * 256 + threadIdx.x;
    if (i < NG * CIN) {
        int g = i >> 10, c = i & (CIN - 1);
        float s = 0.f;
        if (g < 21) {
            #pragma unroll
            for (int k = 0; k < 9; ++k) s += w_cls[(size_t)(g * 9 + k) * CIN + c];
        } else {
            int gr = g - 21;
            #pragma unroll
            for (int k = 0; k < 9; ++k) s += w_reg[(size_t)(gr * 9 + k) * CIN + c];
        }
        Wred[i] = s;
    } else if (i < NG * CIN + NG) {
        int g = i - NG * CIN;
        float s = 0.f;
        if (g < 21) {
            #pragma unroll
            for (int k = 0; k < 9; ++k) s += b_cls[g * 9 + k];
        } else {
            #pragma unroll
            for (int k = 0; k < 9; ++k) s += b_reg[(g - 21) * 9 + k];
        }
        Bred[g] = s;
    }
}

// ---------------- Kernel 2: projection  Z_partial = W' x F (channel chunk) --
// grid = (64 pixel tiles, 16 chunks, B), block = 64 (1 wave, 1 pixel/thread)
// -> 2048 blocks = 8 waves/CU for latency hiding.
// part layout: [chunk][b][g][4096]
__global__ __launch_bounds__(64)
void rfcn_proj(const float* __restrict__ feats,
               const float* __restrict__ Wred,
               float* __restrict__ part) {
    const int p = blockIdx.x * 64 + threadIdx.x;    // pixel in [0,4096)
    const int chunk = blockIdx.y;
    const int b = blockIdx.z;
    const int c0 = chunk * CK;

    const float* __restrict__ f = feats + ((size_t)b * CIN + c0) * HW + p;
    const float* __restrict__ w = Wred + c0;   // uniform indices -> s_load

    float acc[NG];
    #pragma unroll
    for (int g = 0; g < NG; ++g) acc[g] = 0.f;

    #pragma unroll 4
    for (int c = 0; c < CK; ++c) {
        float fv = f[(size_t)c * HW];
        #pragma unroll
        for (int g = 0; g < NG; ++g) acc[g] += fv * w[g * CIN + c];
    }

    float* __restrict__ o = part + ((size_t)(chunk * B + b) * NG) * HW + p;
    #pragma unroll
    for (int g = 0; g < NG; ++g) o[(size_t)g * HW] = acc[g];
}

// ---------------- Kernel 3: reduce + 2D prefix sum + proposal gather -------
// grid = 50 (m = b*25+g), block = 256 (4 waves).
// LDS 64x65: row phase conflict-free via pad; col phase stride 65 == 1
// (mod 32) -> distinct banks per lane.
__global__ __launch_bounds__(256)
void rfcn_integral_gather(const float* __restrict__ part,
                          const int* __restrict__ props,
                          const float* __restrict__ Bred,
                          float* __restrict__ out) {
    const int m = blockIdx.x;        // b*25 + g
    const int t = threadIdx.x;
    const int lane = t & 63;
    const int wave = t >> 6;
    const int b = m / NG;
    const int g = m - b * NG;        // block-uniform
    __shared__ float tile[64 * 65];

    // phase 1: reduce the 16 partial chunks — all 16 loads independent/in-flight
    #pragma unroll 2
    for (int i = 0; i < 16; ++i) {
        const int idx = i * 256 + t;
        float v[NCH];
        #pragma unroll
        for (int ch = 0; ch < NCH; ++ch)
            v[ch] = part[(size_t)(ch * (B * NG) + m) * HW + idx];
        #pragma unroll
        for (int off = NCH / 2; off >= 1; off >>= 1)
            #pragma unroll
            for (int j = 0; j < off; ++j) v[j] += v[j + off];
        tile[(idx >> 6) * 65 + (idx & 63)] = v[0];
    }
    __syncthreads();

    // phase 2: row scans — wave w owns rows [w*16, w*16+16), lane = column
    #pragma unroll 2
    for (int i = 0; i < 16; ++i) {
        const int row = wave * 16 + i;
        float v = tile[row * 65 + lane];
        #pragma unroll
        for (int d = 1; d < 64; d <<= 1) {
            float u = __shfl_up(v, (unsigned)d, 64);
            if (lane >= d) v += u;
        }
        tile[row * 65 + lane] = v;
    }
    __syncthreads();

    // phase 3: column scans — wave w owns cols [w*16, w*16+16), lane = row
    #pragma unroll 2
    for (int i = 0; i < 16; ++i) {
        const int col = wave * 16 + i;
        float v = tile[lane * 65 + col];
        #pragma unroll
        for (int d = 1; d < 64; d <<= 1) {
            float u = __shfl_up(v, (unsigned)d, 64);
            if (lane >= d) v += u;
        }
        tile[lane * 65 + col] = v;
    }
    __syncthreads();

    // phase 4: per-proposal 4-corner lookups straight from LDS
    const float bias = Bred[g];
    #pragma unroll
    for (int i = 0; i < 4; ++i) {
        const int n = i * 256 + t;
        if (n < NPROP) {
            const int4 pr = ((const int4*)props)[b * NPROP + n];
            const int x1 = pr.x >> 5;            // floor(px/32), px >= 0
            const int y1 = pr.y >> 5;
            const int x2 = (pr.z + 31) >> 5;     // ceil
            const int y2 = (pr.w + 31) >> 5;
            const int wb = (x2 - x1 + 2) / 3;    // ceil((x2-x1)/3), >= 1
            const int hb = (y2 - y1 + 2) / 3;
            const int c2 = x1 + wb - 1;          // inclusive corner, <= 63
            const int r2 = y1 + hb - 1;

            float s = tile[r2 * 65 + c2];
            if (x1 > 0)           s -= tile[r2 * 65 + (x1 - 1)];
            if (y1 > 0)           s -= tile[(y1 - 1) * 65 + c2];
            if (x1 > 0 && y1 > 0) s += tile[(y1 - 1) * 65 + (x1 - 1)];
            const float v = bias + s / (float)(hb * wb);
            if (g < 21)  // block-uniform branch
                out[(size_t)(b * NPROP + n) * 21 + g] = v;
            else
                out[(size_t)(B * NPROP * 21) + (size_t)(b * NPROP + n) * 4 + (g - 21)] = v;
        }
    }
}

extern "C" void kernel_launch(void* const* d_in, const int* in_sizes, int n_in,
                              void* d_out, int out_size, void* d_ws, size_t ws_size,
                              hipStream_t stream) {
    const float* feats = (const float*)d_in[0];  // [2,1024,64,64]
    const float* w_cls = (const float*)d_in[1];  // [189,1024]
    const float* b_cls = (const float*)d_in[2];  // [189]
    const float* w_reg = (const float*)d_in[3];  // [36,1024]
    const float* b_reg = (const float*)d_in[4];  // [36]
    const int*   props = (const int*)d_in[5];    // [2,1000,4]
    float* out = (float*)d_out;
    float* ws  = (float*)d_ws;

    // workspace layout (floats): total ~13.3 MB, ws is 268 MB
    float* Wred = ws;                 // 25600
    float* Bred = ws + 25600;         // 25 (partials start at 25632, 128B-aligned)
    float* part = ws + 25632;         // 16 * 2 * 25 * 4096

    rfcn_wfold<<<(NG * CIN + NG + 255) / 256, 256, 0, stream>>>(
        w_cls, b_cls, w_reg, b_reg, Wred, Bred);
    rfcn_proj<<<dim3(HW / 64, NCH, B), 64, 0, stream>>>(feats, Wred, part);
    rfcn_integral_gather<<<B * NG, 256, 0, stream>>>(part, props, Bred, out);
}